// Round 1
// baseline (572.251 us; speedup 1.0000x reference)
//
#include <hip/hip_runtime.h>

#define NN 50000
#define DD 64
#define BB 32

// Pass 1: p[b,n] = adj[n] ? exp(leaky_relu(tgt[b] + x[b,n,:].a_src)) : 0
// write p to out, accumulate per-b sum into sums[b] (pre-zeroed).
__global__ __launch_bounds__(256) void attn_pass1(
    const float* __restrict__ x, const float* __restrict__ a,
    const int* __restrict__ node_index, const int* __restrict__ adj,
    float* __restrict__ out, float* __restrict__ sums)
{
    const int tid = threadIdx.x;
    const int b = blockIdx.y;
    const int node = *node_index;

    __shared__ float sh_tgt;
    __shared__ float sh_part[4];

    // target score: dot(x[b,node,:], a[:64]) — computed by wave 0
    if (tid < 64) {
        float v = x[(size_t)b * NN * DD + (size_t)node * DD + tid] * a[tid];
        #pragma unroll
        for (int o = 32; o >= 1; o >>= 1) v += __shfl_xor(v, o, 64);
        if (tid == 0) sh_tgt = v;
    }
    __syncthreads();
    const float tgt = sh_tgt;

    const int wave = tid >> 6;   // 0..3
    const int lane = tid & 63;
    const int g = lane >> 4;     // row-within-group 0..3
    const int c = lane & 15;     // 16 lanes x float4 = 64 floats per row

    const float4 av = ((const float4*)(a + DD))[c];  // a_src fragment

    float local = 0.f;
    const int rowBase = blockIdx.x * 256;
    const float* xb = x + (size_t)b * NN * DD;

    #pragma unroll 4
    for (int i = 0; i < 16; i++) {
        const int row = rowBase + i * 16 + wave * 4 + g;
        float s = 0.f;
        if (row < NN) {
            const float4 xv = ((const float4*)(xb + (size_t)row * DD))[c];
            s = xv.x * av.x + xv.y * av.y + xv.z * av.z + xv.w * av.w;
        }
        // reduce across the 16 lanes of this row group
        s += __shfl_xor(s, 1, 64);
        s += __shfl_xor(s, 2, 64);
        s += __shfl_xor(s, 4, 64);
        s += __shfl_xor(s, 8, 64);
        if (c == 0 && row < NN) {
            const float z = tgt + s;
            const float e = (z > 0.f) ? z : 0.01f * z;
            const float p = (adj[row] > 0) ? __expf(e) : 0.f;
            out[(size_t)b * NN + row] = p;
            local += p;
        }
    }

    // block-level sum of local (nonzero only on c==0 lanes)
    #pragma unroll
    for (int o = 32; o >= 1; o >>= 1) local += __shfl_xor(local, o, 64);
    if (lane == 0) sh_part[wave] = local;
    __syncthreads();
    if (tid == 0)
        atomicAdd(&sums[b], sh_part[0] + sh_part[1] + sh_part[2] + sh_part[3]);
}

// Pass 2: out[b,n] /= sums[b]   (float4-vectorized)
__global__ __launch_bounds__(256) void attn_pass2(
    float* __restrict__ out, const float* __restrict__ sums)
{
    const int N4 = NN / 4;  // 12500
    const int f = blockIdx.x * blockDim.x + threadIdx.x;
    const int b = blockIdx.y;
    if (f < N4) {
        const float inv = 1.0f / sums[b];
        float4* p = (float4*)out + (size_t)b * N4 + f;
        float4 v = *p;
        v.x *= inv; v.y *= inv; v.z *= inv; v.w *= inv;
        *p = v;
    }
}

extern "C" void kernel_launch(void* const* d_in, const int* in_sizes, int n_in,
                              void* d_out, int out_size, void* d_ws, size_t ws_size,
                              hipStream_t stream) {
    const float* x = (const float*)d_in[0];         // (B, N, D) fp32
    const float* a = (const float*)d_in[1];         // (2D, 1) fp32
    const int* node_index = (const int*)d_in[2];    // scalar
    const int* adj = (const int*)d_in[3];           // (N,) int32
    float* out = (float*)d_out;                     // (B, N) fp32
    float* sums = (float*)d_ws;                     // 32 floats of scratch

    hipMemsetAsync(sums, 0, BB * sizeof(float), stream);

    dim3 g1((NN + 255) / 256, BB);
    attn_pass1<<<g1, 256, 0, stream>>>(x, a, node_index, adj, out, sums);

    dim3 g2((NN / 4 + 255) / 256, BB);
    attn_pass2<<<g2, 256, 0, stream>>>(out, sums);
}

// Round 2
// 550.466 us; speedup vs baseline: 1.0396x; 1.0396x over previous
//
#include <hip/hip_runtime.h>

#define NN 50000
#define DD 64
#define BB 32

// Pass 1: p[b,n] = adj[n] ? exp(leaky_relu(tgt[b] + x[b,n,:].a_src)) : 0
// Key trick: if adj[n]==0 we skip the 256 B row load of x entirely (~50% of rows).
__global__ __launch_bounds__(256) void attn_pass1(
    const float* __restrict__ x, const float* __restrict__ a,
    const int* __restrict__ node_index, const int* __restrict__ adj,
    float* __restrict__ out, float* __restrict__ sums)
{
    const int tid = threadIdx.x;
    const int b = blockIdx.y;
    const int node = *node_index;

    __shared__ float sh_tgt;
    __shared__ float sh_part[4];

    // target score: dot(x[b,node,:], a[:64]) — wave 0 (L2-hot after first block)
    if (tid < 64) {
        float v = x[(size_t)b * NN * DD + (size_t)node * DD + tid] * a[tid];
        #pragma unroll
        for (int o = 32; o >= 1; o >>= 1) v += __shfl_xor(v, o, 64);
        if (tid == 0) sh_tgt = v;
    }
    __syncthreads();
    const float tgt = sh_tgt;

    const int wave = tid >> 6;   // 0..3
    const int lane = tid & 63;
    const int g = lane >> 4;     // row-within-group 0..3
    const int c = lane & 15;     // 16 lanes x float4 = 64 floats per row

    const float4 av = ((const float4*)(a + DD))[c];  // a_src fragment

    float local = 0.f;
    const int rowBase = blockIdx.x * 256;
    const float* xb = x + (size_t)b * NN * DD;

    #pragma unroll 4
    for (int i = 0; i < 16; i++) {
        const int row = rowBase + i * 16 + wave * 4 + g;
        const bool valid = (row < NN);
        // all 16 lanes of a row-group hit the same address -> broadcast, 1 txn
        const int msk = valid ? adj[row] : 0;

        float s = 0.f;
        if (msk > 0) {  // skip the 256 B x-row entirely for masked rows
            const float4 xv = ((const float4*)(xb + (size_t)row * DD))[c];
            s = xv.x * av.x + xv.y * av.y + xv.z * av.z + xv.w * av.w;
        }
        // reduce across the 16 lanes of this row group (s==0 uniformly if masked)
        s += __shfl_xor(s, 1, 64);
        s += __shfl_xor(s, 2, 64);
        s += __shfl_xor(s, 4, 64);
        s += __shfl_xor(s, 8, 64);

        if (c == 0 && valid) {
            float p = 0.f;
            if (msk > 0) {
                const float z = tgt + s;
                const float e = (z > 0.f) ? z : 0.01f * z;
                p = __expf(e);
            }
            out[(size_t)b * NN + row] = p;
            local += p;
        }
    }

    // block-level sum of local (nonzero only on c==0 lanes)
    #pragma unroll
    for (int o = 32; o >= 1; o >>= 1) local += __shfl_xor(local, o, 64);
    if (lane == 0) sh_part[wave] = local;
    __syncthreads();
    if (tid == 0)
        atomicAdd(&sums[b], sh_part[0] + sh_part[1] + sh_part[2] + sh_part[3]);
}

// Pass 2: out[b,n] /= sums[b]   (float4-vectorized, ~12.8 MB RW, ~3 µs)
__global__ __launch_bounds__(256) void attn_pass2(
    float* __restrict__ out, const float* __restrict__ sums)
{
    const int N4 = NN / 4;  // 12500
    const int f = blockIdx.x * blockDim.x + threadIdx.x;
    const int b = blockIdx.y;
    if (f < N4) {
        const float inv = 1.0f / sums[b];
        float4* p = (float4*)out + (size_t)b * N4 + f;
        float4 v = *p;
        v.x *= inv; v.y *= inv; v.z *= inv; v.w *= inv;
        *p = v;
    }
}

extern "C" void kernel_launch(void* const* d_in, const int* in_sizes, int n_in,
                              void* d_out, int out_size, void* d_ws, size_t ws_size,
                              hipStream_t stream) {
    const float* x = (const float*)d_in[0];         // (B, N, D) fp32
    const float* a = (const float*)d_in[1];         // (2D, 1) fp32
    const int* node_index = (const int*)d_in[2];    // scalar
    const int* adj = (const int*)d_in[3];           // (N,) int32
    float* out = (float*)d_out;                     // (B, N) fp32
    float* sums = (float*)d_ws;                     // 32 floats of scratch

    hipMemsetAsync(sums, 0, BB * sizeof(float), stream);

    dim3 g1((NN + 255) / 256, BB);
    attn_pass1<<<g1, 256, 0, stream>>>(x, a, node_index, adj, out, sums);

    dim3 g2((NN / 4 + 255) / 256, BB);
    attn_pass2<<<g2, 256, 0, stream>>>(out, sums);
}